// Round 11
// baseline (156.267 us; speedup 1.0000x reference)
//
#include <hip/hip_runtime.h>
#include <math.h>

#define NT_ 365
#define NS_ 1024
#define NH_ 64
#define NG_ 32
#define NW_ 514        // NH*8 + 2
#define SEG_ 96        // segment stride: segs 0-2 own 96 steps, seg 3 owns 77
#define CH_ 16         // full-phase chunk length (ytile rows)
#define YPAD_ 68       // row stride (floats): 16B-aligned rows, conflict-free
#define NTPAD_ 384     // met buffer padded past 365 with zeros

__device__ __forceinline__ float sigmoidf(float v) {
  return 1.0f / (1.0f + expf(-v));
}

// met = (Ps, Pl, relu(Ta), E); relu folded here since gm > 0
__device__ __forceinline__ float4 compute_met(float4 xv) {
  const float P = xv.x, E = xv.y, T1 = xv.z, T2 = xv.w;
  const float Ta = (T1 + T2) * 0.5f;
  float rP;
  if (T2 <= 0.0f) {
    rP = 0.0f;
  } else if (T1 >= 0.0f) {
    rP = 1.0f;
  } else {
    float r = (T1 + T2) / (T2 - T1);
    r = fminf(fmaxf(r, -0.999999f), 0.999999f);
    rP = 1.0f - acosf(r) * (1.0f / 3.1415f);
  }
  float4 m;
  m.x = (1.0f - rP) * P;   // Ps
  m.y = rP * P;            // Pl
  m.z = fmaxf(Ta, 0.0f);   // relu(Ta)
  m.w = E;
  return m;
}

// ---- segmented scan with line-local I/O -----------------------------------
// Block = 1024 threads = 16 waves = 4 adjacent sites x 4 time segments.
// The 4 sites sharing each 64B x/out cache line live in ONE block (R4's
// locality, 6.3MB fetch), while segmentation gives 4 waves/SIMD machine-wide
// (R10's occupancy win). Wave wv: site blk*4+(wv&3), segment wv>>2; each SIMD
// hosts one wave of every segment length -> balanced tail.
__global__ __launch_bounds__(1024, 1) void waternet_scan(
    const float* __restrict__ x,     // [NT, NS, 4]
    const float* __restrict__ xc,    // [NS, NG]
    const float* __restrict__ fc_w,  // [NW, NG]
    const float* __restrict__ fc_b,  // [NW]
    float* __restrict__ out)         // [NT, NS]
{
  __shared__ float4 smet[4][NTPAD_];          // 24 KB: [siteLocal][t]
  __shared__ float  ytile[16][CH_ * YPAD_];   // 69.6 KB: per-wave y transpose

  const int tid  = threadIdx.x;
  const int lane = tid & 63;
  const int wv   = tid >> 6;          // 0..15
  const int sloc = wv & 3;            // site within block
  const int seg  = wv >> 2;           // time segment 0..3
  const int sbase = blockIdx.x << 2;  // first site of this block
  const int site  = sbase + sloc;
  const float4* xp = (const float4*)x;

  // ---- staged x loads issued FIRST (latency hidden under the GEMM).
  // thread e covers (site sbase+(e&3), t=e>>2): consecutive lanes sweep a
  // full 64B line (4 sites x 16B) exactly once -> minimal HBM fetch.
  const int   sA = tid & 3,        tA = tid >> 2;          // t = 0..255
  const int   sB = tid & 3,        tB = 256 + (tid >> 2);  // t = 256..511 (use <384)
  const float4 xa = xp[tA * NS_ + sbase + sA];
  float4 xb = make_float4(0.0f, 0.0f, 0.0f, 0.0f);
  const bool bvalid = (tB < NT_);
  if (bvalid) xb = xp[tB * NS_ + sbase + sB];

  // ---- gate GEMM (redundant across the 4 segments of a site)
  float acc[8];
#pragma unroll
  for (int k = 0; k < 8; ++k) acc[k] = fc_b[k * NH_ + lane];
  float accq = fc_b[NW_ - 1];

  const float4* xcq = (const float4*)(xc + site * NG_);
  const float4* wq4 = (const float4*)fc_w;
#pragma unroll
  for (int g4 = 0; g4 < NG_ / 4; ++g4) {
    const float4 xv = xcq[g4];
#pragma unroll
    for (int k = 0; k < 8; ++k) {
      const float4 w = wq4[(k * NH_ + lane) * (NG_ / 4) + g4];
      acc[k] = fmaf(xv.x, w.x, acc[k]);
      acc[k] = fmaf(xv.y, w.y, acc[k]);
      acc[k] = fmaf(xv.z, w.z, acc[k]);
      acc[k] = fmaf(xv.w, w.w, acc[k]);
    }
    {
      const float4 w = wq4[(NW_ - 1) * (NG_ / 4) + g4];
      accq = fmaf(xv.x, w.x, accq);
      accq = fmaf(xv.y, w.y, accq);
      accq = fmaf(xv.z, w.z, accq);
      accq = fmaf(xv.w, w.w, accq);
    }
  }

  // ---- gates (per-lane = per hidden unit)
  const float gm = expf(acc[0]) + 1.0f;
  const float ge = sigmoidf(acc[1]) * 2.0f;
  const float go = sigmoidf(acc[2]);
  const float gl = expf(acc[3] * 2.0f);
  float mx = acc[4];
#pragma unroll
  for (int mm = 32; mm >= 1; mm >>= 1) mx = fmaxf(mx, __shfl_xor(mx, mm, 64));
  const float ex = expf(acc[4] - mx);
  float sm = ex;
#pragma unroll
  for (int mm = 32; mm >= 1; mm >>= 1) sm += __shfl_xor(sm, mm, 64);
  const float ga = ex / sm;
  const float gb = sigmoidf(acc[5]);
  const float kb = sigmoidf(acc[6]) * 0.1f;
  const float gi = sigmoidf(acc[7]);
  const float qb = fmaxf(accq, 0.0f) * (1.0f / NH_);
  const float kb1m = 1.0f - kb;                 // G0' = G*(1-kb)
  const float nge  = -ge;
  const float gq1  = go * (1.0f - gb) - 1.0f;   // y = ga*(H + M*gq1 + G*kb)

  // ---- stage met to LDS (zeros for t in [365, 384))
  smet[sA][tA] = compute_met(xa);
  if (tB < NTPAD_)
    smet[sB][tB] = bvalid ? compute_met(xb)
                          : make_float4(0.0f, 0.0f, 0.0f, 0.0f);
  __syncthreads();

  // ---- scan state
  float S0 = 0.0f, H0 = 0.0f, G0 = 0.0f;
  const float4* mrow = &smet[sloc][0];

  // ---- light pre-scan: steps [0, 96*seg), state only (~15 instr/step)
  const int lim = seg * SEG_;                // 0, 96, 192, 288 (all %8 == 0)
  for (int tt = 0; tt < lim; tt += 8) {
    float4 mb[8];
#pragma unroll
    for (int u = 0; u < 8; ++u) mb[u] = mrow[tt + u];
#pragma unroll
    for (int u = 0; u < 8; ++u) {
      const float4 mt = mb[u];
      const float melt = mt.z * gm;
      const float Sm   = fminf(S0, melt);
      const float base = H0 + Sm;
      S0 = (S0 - Sm) + mt.x;
      const float H = fmaxf(fmaf(mt.w, nge, fmaf(mt.y, gi, base)), 0.0f);
      const float M = fminf(H, gl);
      const float Q2a = M * go;
      H0 = fminf(H - Q2a, gl);
      G0 = fmaf(Q2a, gb, G0) * kb1m;
    }
  }

  // ---- full phase: this wave owns steps [96*seg, 96*seg+96) (seg 3: 77)
  const int nch = (seg == 3) ? 5 : 6;        // wave-uniform trip count
  float*       yw = &ytile[wv][lane];        // step j writes yw[j*YPAD_]
  const float* yr = &ytile[wv][lane * YPAD_];

  for (int cc = 0; cc < nch; ++cc) {
    const float4* mp = &mrow[lim + cc * CH_];
#pragma unroll
    for (int j = 0; j < CH_; ++j) {
      const float4 mt = mp[j];               // ds_read_b128, imm offset
      const float melt = mt.z * gm;
      const float Sm   = fminf(S0, melt);
      const float base = H0 + Sm;
      S0 = (S0 - Sm) + mt.x;
      const float H = fmaxf(fmaf(mt.w, nge, fmaf(mt.y, gi, base)), 0.0f);
      const float M = fminf(H, gl);
      const float Q2a = M * go;
      H0 = fminf(H - Q2a, gl);
      const float G = fmaf(Q2a, gb, G0);
      G0 = G * kb1m;
      yw[j * YPAD_] = fmaf(G, kb, fmaf(M, gq1, H)) * ga;  // ds_write_b32
    }
    // transposed reduce: lane j (<16) sums row j via 16 b128 reads
    if (lane < CH_) {
      const float4* yv = (const float4*)yr;  // rows are 16B-aligned (YPAD=68)
      float4 r0 = yv[0], r1 = yv[1], r2 = yv[2], r3 = yv[3];
#pragma unroll
      for (int h = 4; h < 16; h += 4) {
        r0 += yv[h + 0];
        r1 += yv[h + 1];
        r2 += yv[h + 2];
        r3 += yv[h + 3];
      }
      const float4 rs = (r0 + r1) + (r2 + r3);
      const float tot = (rs.x + rs.y) + (rs.z + rs.w);
      const int t_out = lim + cc * CH_ + lane;
      if (t_out < NT_) out[t_out * NS_ + site] = tot + qb;
    }
  }
}

extern "C" void kernel_launch(void* const* d_in, const int* in_sizes, int n_in,
                              void* d_out, int out_size, void* d_ws, size_t ws_size,
                              hipStream_t stream) {
  const float* x    = (const float*)d_in[0];
  const float* xc   = (const float*)d_in[1];
  const float* fc_w = (const float*)d_in[2];
  const float* fc_b = (const float*)d_in[3];
  float* out = (float*)d_out;

  // 256 blocks x 1024 threads: 1 block/CU, 16 waves = 4 waves/SIMD,
  // 4 adjacent sites per block (cache-line-local I/O) x 4 segments.
  hipLaunchKernelGGL(waternet_scan, dim3(NS_ / 4), dim3(1024), 0, stream,
                     x, xc, fc_w, fc_b, out);
}

// Round 12
// 136.998 us; speedup vs baseline: 1.1407x; 1.1407x over previous
//
#include <hip/hip_runtime.h>
#include <math.h>

#define NT_ 365
#define NS_ 1024
#define NH_ 64
#define NG_ 32
#define NW_ 514        // NH*8 + 2
#define SEG_ 96        // segs 0-2 own 96 steps, seg 3 owns 77 (+3 pad)
#define CH_ 16         // full-phase chunk length (ytile rows)
#define YPAD_ 66       // y row stride (floats): b64-aligned rows, conflict-free
#define NTPAD_ 368     // met buffer length (365 rounded up to 16)

__device__ __forceinline__ float sigmoidf(float v) {
  return 1.0f / (1.0f + expf(-v));
}

// met = (Ps, Pl, relu(Ta), E); relu folded here since gm > 0
__device__ __forceinline__ float4 compute_met(float4 xv) {
  const float P = xv.x, E = xv.y, T1 = xv.z, T2 = xv.w;
  const float Ta = (T1 + T2) * 0.5f;
  float rP;
  if (T2 <= 0.0f) {
    rP = 0.0f;
  } else if (T1 >= 0.0f) {
    rP = 1.0f;
  } else {
    float r = (T1 + T2) / (T2 - T1);
    r = fminf(fmaxf(r, -0.999999f), 0.999999f);
    rP = 1.0f - acosf(r) * (1.0f / 3.1415f);
  }
  float4 m;
  m.x = (1.0f - rP) * P;   // Ps
  m.y = rP * P;            // Pl
  m.z = fmaxf(Ta, 0.0f);   // relu(Ta)
  m.w = E;
  return m;
}

// ---- segmented scan, spill-free -------------------------------------------
// Block = 256 thr = 4 waves = 4 adjacent sites x ONE segment. Grid = 1024:
// g = blk&255 (site group), seg = blk>>8. Round-robin dispatch puts blocks
// {c, c+256, c+512, c+768} on CU c -> all 4 segments of one group per CU:
// balanced load, x lines fetched once per CU, 4 waves/SIMD at VGPR<=128.
// NO min-waves launch-bounds clause: R10/R11's (.,4)/(1024,1) capped the
// allocator at 64 VGPRs and the resulting spill traffic (88MB fetch / 167MB
// write of scratch) WAS the regression.
__global__ __launch_bounds__(256) void waternet_scan(
    const float* __restrict__ x,     // [NT, NS, 4]
    const float* __restrict__ xc,    // [NS, NG]
    const float* __restrict__ fc_w,  // [NW, NG]
    const float* __restrict__ fc_b,  // [NW]
    float* __restrict__ out)         // [NT, NS]
{
  __shared__ float4 smet[4][NTPAD_];          // 23 KB: [siteLocal][t]
  __shared__ float  ytile[4][CH_ * YPAD_];    // 16.9 KB: per-wave y transpose

  const int tid  = threadIdx.x;
  const int lane = tid & 63;
  const int wv   = tid >> 6;                  // site within group (0..3)
  const int g    = blockIdx.x & 255;          // site group
  const int seg  = blockIdx.x >> 8;           // time segment (0..3)
  const int sb4  = g << 2;
  const int site = sb4 + wv;
  const int us   = __builtin_amdgcn_readfirstlane(site);
  const float4* xp = (const float4*)x;

  // ---- staged x loads issued FIRST (latency hidden under the GEMM).
  // round r, thread e -> (site sb4+(e&3), t=(r*256+e)>>2): 4 lanes sweep a
  // full 64B line; fully coalesced, each line touched once per block.
  float4 xs[6];
#pragma unroll
  for (int r = 0; r < 6; ++r) {
    const int idx = r * 256 + tid;
    const int s = idx & 3, t = idx >> 2;
    xs[r] = (t < NT_) ? xp[t * NS_ + sb4 + s]
                      : make_float4(0.0f, 0.0f, 0.0f, 0.0f);
  }

  // ---- gate GEMM (redundant across the 4 segment-blocks of this site)
  float acc[8];
#pragma unroll
  for (int k = 0; k < 8; ++k) acc[k] = fc_b[k * NH_ + lane];
  float accq = fc_b[NW_ - 1];

  const float4* xcq = (const float4*)(xc + us * NG_);
  const float4* wq4 = (const float4*)fc_w;
#pragma unroll
  for (int g4 = 0; g4 < NG_ / 4; ++g4) {
    const float4 xv = xcq[g4];
#pragma unroll
    for (int k = 0; k < 8; ++k) {
      const float4 w = wq4[(k * NH_ + lane) * (NG_ / 4) + g4];
      acc[k] = fmaf(xv.x, w.x, acc[k]);
      acc[k] = fmaf(xv.y, w.y, acc[k]);
      acc[k] = fmaf(xv.z, w.z, acc[k]);
      acc[k] = fmaf(xv.w, w.w, acc[k]);
    }
    {
      const float4 w = wq4[(NW_ - 1) * (NG_ / 4) + g4];
      accq = fmaf(xv.x, w.x, accq);
      accq = fmaf(xv.y, w.y, accq);
      accq = fmaf(xv.z, w.z, accq);
      accq = fmaf(xv.w, w.w, accq);
    }
  }

  // ---- gates (per-lane = per hidden unit)
  const float gm = expf(acc[0]) + 1.0f;
  const float ge = sigmoidf(acc[1]) * 2.0f;
  const float go = sigmoidf(acc[2]);
  const float gl = expf(acc[3] * 2.0f);
  float mx = acc[4];
#pragma unroll
  for (int mm = 32; mm >= 1; mm >>= 1) mx = fmaxf(mx, __shfl_xor(mx, mm, 64));
  const float ex = expf(acc[4] - mx);
  float sm = ex;
#pragma unroll
  for (int mm = 32; mm >= 1; mm >>= 1) sm += __shfl_xor(sm, mm, 64);
  const float ga = ex / sm;
  const float gb = sigmoidf(acc[5]);
  const float kb = sigmoidf(acc[6]) * 0.1f;
  const float gi = sigmoidf(acc[7]);
  const float qb = fmaxf(accq, 0.0f) * (1.0f / NH_);
  const float kb1m = 1.0f - kb;                 // G0' = G*(1-kb)
  const float nge  = -ge;
  const float gq1  = go * (1.0f - gb) - 1.0f;   // y = ga*(H + M*gq1 + G*kb)

  // ---- stage met to LDS (zeros for t in [365, 368))
#pragma unroll
  for (int r = 0; r < 6; ++r) {
    const int idx = r * 256 + tid;
    const int s = idx & 3, t = idx >> 2;
    if (t < NTPAD_)
      smet[s][t] = (t < NT_) ? compute_met(xs[r])
                             : make_float4(0.0f, 0.0f, 0.0f, 0.0f);
  }
  __syncthreads();

  // ---- scan state
  float S0 = 0.0f, H0 = 0.0f, G0 = 0.0f;
  const float4* mrow = &smet[wv][0];

  // ---- light pre-scan: steps [0, 96*seg), state only (~15 instr/step)
  const int lim = seg * SEG_;                // 0, 96, 192, 288 (all %8 == 0)
  for (int tt = 0; tt < lim; tt += 8) {
    float4 mb[8];
#pragma unroll
    for (int u = 0; u < 8; ++u) mb[u] = mrow[tt + u];
#pragma unroll
    for (int u = 0; u < 8; ++u) {
      const float4 mt = mb[u];
      const float melt = mt.z * gm;
      const float Sm   = fminf(S0, melt);
      const float base = H0 + Sm;
      S0 = (S0 - Sm) + mt.x;
      const float H = fmaxf(fmaf(mt.w, nge, fmaf(mt.y, gi, base)), 0.0f);
      const float M = fminf(H, gl);
      const float Q2a = M * go;
      H0 = fminf(H - Q2a, gl);
      G0 = fmaf(Q2a, gb, G0) * kb1m;
    }
  }

  // ---- full phase: steps [96*seg, 96*seg+96) (seg 3: 77 real + 3 pad)
  const int nch = (seg == 3) ? 5 : 6;        // block-uniform trip count
  float*       yw = &ytile[wv][lane];        // step j writes yw[j*YPAD_]
  const float* yr = &ytile[wv][lane * YPAD_];

  for (int cc = 0; cc < nch; ++cc) {
    const float4* mp = &mrow[lim + cc * CH_];
#pragma unroll
    for (int j = 0; j < CH_; ++j) {
      const float4 mt = mp[j];               // ds_read_b128, imm offset
      const float melt = mt.z * gm;
      const float Sm   = fminf(S0, melt);
      const float base = H0 + Sm;
      S0 = (S0 - Sm) + mt.x;
      const float H = fmaxf(fmaf(mt.w, nge, fmaf(mt.y, gi, base)), 0.0f);
      const float M = fminf(H, gl);
      const float Q2a = M * go;
      H0 = fminf(H - Q2a, gl);
      const float G = fmaf(Q2a, gb, G0);
      G0 = G * kb1m;
      yw[j * YPAD_] = fmaf(G, kb, fmaf(M, gq1, H)) * ga;  // ds_write_b32
    }
    // transposed reduce: lane j (<16) sums row j via 32 b64 reads
    // (write bank=(lane+2j)%32: 2-way, free; read bank=2(lane+h)%32: clean)
    if (lane < CH_) {
      const float2* yv = (const float2*)yr;  // rows are 8B-aligned (YPAD=66)
      float r0 = 0.0f, r1 = 0.0f, r2 = 0.0f, r3 = 0.0f;
#pragma unroll
      for (int h = 0; h < 32; h += 4) {
        const float2 a = yv[h + 0], b = yv[h + 1];
        const float2 c = yv[h + 2], d = yv[h + 3];
        r0 += a.x + a.y;
        r1 += b.x + b.y;
        r2 += c.x + c.y;
        r3 += d.x + d.y;
      }
      const float tot = (r0 + r1) + (r2 + r3);
      const int t_out = lim + cc * CH_ + lane;
      if (t_out < NT_) out[t_out * NS_ + site] = tot + qb;
    }
  }
}

extern "C" void kernel_launch(void* const* d_in, const int* in_sizes, int n_in,
                              void* d_out, int out_size, void* d_ws, size_t ws_size,
                              hipStream_t stream) {
  const float* x    = (const float*)d_in[0];
  const float* xc   = (const float*)d_in[1];
  const float* fc_w = (const float*)d_in[2];
  const float* fc_b = (const float*)d_in[3];
  float* out = (float*)d_out;

  // 1024 blocks x 256 thr: group = blk&255, segment = blk>>8 -> round-robin
  // dispatch gives each CU all 4 segments of one site group (balanced, local).
  hipLaunchKernelGGL(waternet_scan, dim3(1024), dim3(256), 0, stream,
                     x, xc, fc_w, fc_b, out);
}

// Round 13
// 89.488 us; speedup vs baseline: 1.7462x; 1.5309x over previous
//
#include <hip/hip_runtime.h>
#include <math.h>

#define NT_ 365
#define NS_ 1024
#define NH_ 64
#define NG_ 32
#define NW_ 514        // NH*8 + 2
#define CH_ 64         // timesteps per chunk (= wave size)
#define NCHUNK_ 6      // ceil(365/64); tail steps are harmless dummies
#define YPAD_ 65       // padded row stride: bank = (lane+j)%32, conflict-free R/W
#define SB_ 16         // sub-batch: met-dependent terms hoisted to registers

__device__ __forceinline__ float sigmoidf(float v) {
  return 1.0f / (1.0f + expf(-v));
}

// met = (Ps, Pl, relu(Ta), E); relu folded here since gm > 0
__device__ __forceinline__ float4 compute_met(float4 xv) {
  const float P = xv.x, E = xv.y, T1 = xv.z, T2 = xv.w;
  const float Ta = (T1 + T2) * 0.5f;
  float rP;
  if (T2 <= 0.0f) {
    rP = 0.0f;
  } else if (T1 >= 0.0f) {
    rP = 1.0f;
  } else {
    float r = (T1 + T2) / (T2 - T1);
    r = fminf(fmaxf(r, -0.999999f), 0.999999f);
    rP = 1.0f - acosf(r) * (1.0f / 3.1415f);
  }
  float4 m;
  m.x = (1.0f - rP) * P;   // Ps
  m.y = rP * P;            // Pl
  m.z = fmaxf(Ta, 0.0f);   // relu(Ta)
  m.w = E;
  return m;
}

// One wave per site (1024 waves = 1/SIMD machine-wide; sites==SIMDs so this
// is the max spread — R5/R10-R12 proved extra waves/SIMD only interfere).
// Lone-wave cost ~10.5 cyc/instr (R4/R7/R8 invariant): so minimize in-chain
// instructions. Per 16-step sub-batch, all met-dependent math (melt, addin,
// Ps) is hoisted into a phase-1 burst of independent ops; the recurrence
// steps shrink to ~12 instr. Occupancy is irrelevant -> VGPRs are free
// (NO min-waves launch-bounds clause: R10/R11's cap caused spill traffic).
__global__ __launch_bounds__(256) void waternet_scan(
    const float* __restrict__ x,     // [NT, NS, 4]
    const float* __restrict__ xc,    // [NS, NG]
    const float* __restrict__ fc_w,  // [NW, NG]
    const float* __restrict__ fc_b,  // [NW]
    float* __restrict__ out)         // [NT, NS]
{
  __shared__ float4 smet[4][CH_];          // 4 KB:  [wave][step] met
  __shared__ float  ytile[4][CH_ * YPAD_]; // 66.6 KB: per-wave y rows

  const int tid  = threadIdx.x;
  const int lane = tid & 63;
  const int wv   = tid >> 6;
  const int site = (blockIdx.x << 2) + wv;
  const int us   = __builtin_amdgcn_readfirstlane(site);
  const float4* xp = (const float4*)x;

  // chunk-0 prefetch first: HBM latency hides under the gate GEMM
  float4 xcur = xp[lane * NS_ + site];  // t = lane

  // ---- prologue GEMM: w[site, j] = xc[site,:] . fc_w[j,:] + fc_b[j]
  float acc[8];
#pragma unroll
  for (int k = 0; k < 8; ++k) acc[k] = fc_b[k * NH_ + lane];
  float accq = fc_b[NW_ - 1];

  const float4* xcq = (const float4*)(xc + us * NG_);
  const float4* wq4 = (const float4*)fc_w;
#pragma unroll
  for (int g4 = 0; g4 < NG_ / 4; ++g4) {
    const float4 xv = xcq[g4];
#pragma unroll
    for (int k = 0; k < 8; ++k) {
      const float4 w = wq4[(k * NH_ + lane) * (NG_ / 4) + g4];
      acc[k] = fmaf(xv.x, w.x, acc[k]);
      acc[k] = fmaf(xv.y, w.y, acc[k]);
      acc[k] = fmaf(xv.z, w.z, acc[k]);
      acc[k] = fmaf(xv.w, w.w, acc[k]);
    }
    {
      const float4 w = wq4[(NW_ - 1) * (NG_ / 4) + g4];
      accq = fmaf(xv.x, w.x, accq);
      accq = fmaf(xv.y, w.y, accq);
      accq = fmaf(xv.z, w.z, accq);
      accq = fmaf(xv.w, w.w, accq);
    }
  }

  // ---- gates (per-lane = per hidden unit)
  const float gm = expf(acc[0]) + 1.0f;
  const float ge = sigmoidf(acc[1]) * 2.0f;
  const float go = sigmoidf(acc[2]);
  const float gl = expf(acc[3] * 2.0f);
  float mx = acc[4];
#pragma unroll
  for (int mm = 32; mm >= 1; mm >>= 1) mx = fmaxf(mx, __shfl_xor(mx, mm, 64));
  const float ex = expf(acc[4] - mx);
  float sm = ex;
#pragma unroll
  for (int mm = 32; mm >= 1; mm >>= 1) sm += __shfl_xor(sm, mm, 64);
  const float ga = ex / sm;
  const float gb = sigmoidf(acc[5]);
  const float kb = sigmoidf(acc[6]) * 0.1f;
  const float gi = sigmoidf(acc[7]);
  const float qb = fmaxf(accq, 0.0f) * (1.0f / NH_);
  const float kb1m = 1.0f - kb;                 // G0' = G*(1-kb)
  const float nge  = -ge;
  const float gq1  = go * (1.0f - gb) - 1.0f;   // y = ga*(H + M*gq1 + G*kb)

  // ---- scan state
  float S0 = 0.0f, H0 = 0.0f, G0 = 0.0f;

  // stage chunk-0 met (lane = step); per-wave slice + in-order DS -> no barrier
  smet[wv][lane] = compute_met(xcur);

  float*       yw = &ytile[wv][lane];          // step j writes yw[j*YPAD_]
  const float* yr = &ytile[wv][lane * YPAD_];  // reduce: lane sums its row

#pragma unroll 1   // keep body I-cache resident across the 6 iterations
  for (int c = 0; c < NCHUNK_; ++c) {
    // prefetch chunk c+1 from HBM (clamped dummy tail) — in flight all chunk
    int tn = (c + 1) * CH_ + lane;
    tn = (tn < NT_) ? tn : (NT_ - 1);
    const float4 xnext = xp[tn * NS_ + site];

    const float4* mp = &smet[wv][0];

#pragma unroll
    for (int sb = 0; sb < CH_ / SB_; ++sb) {
      // ---- phase 1: met-dependent terms, chain-independent burst ----------
      float melt[SB_], addin[SB_], Ps[SB_];
#pragma unroll
      for (int u = 0; u < SB_; ++u) {
        const float4 mt = mp[sb * SB_ + u];      // ds_read_b128, imm offset
        melt[u]  = mt.z * gm;                    // relu(Ta)*gm
        addin[u] = fmaf(mt.y, gi, mt.w * nge);   // Pl*gi - E*ge
        Ps[u]    = mt.x;
      }
      // ---- phase 2: the recurrence, ~12 instr/step ------------------------
#pragma unroll
      for (int u = 0; u < SB_; ++u) {
        const float Sm   = fminf(S0, melt[u]);
        const float base = H0 + Sm;
        S0 = (S0 - Sm) + Ps[u];
        const float H = fmaxf(base + addin[u], 0.0f);
        const float M = fminf(H, gl);
        const float Q2a = M * go;
        H0 = fminf(H - Q2a, gl);
        const float G = fmaf(Q2a, gb, G0);
        G0 = G * kb1m;
        yw[(sb * SB_ + u) * YPAD_] =
            fmaf(G, kb, fmaf(M, gq1, H)) * ga;   // ds_write_b32, imm offset
      }
    }

    // ---- transposed reduction: lane t' sums row t' (bank=(t'+h)%32, free)
    float r0 = 0.0f, r1 = 0.0f, r2 = 0.0f, r3 = 0.0f;
#pragma unroll
    for (int h = 0; h < CH_; h += 4) {
      r0 += yr[h + 0];
      r1 += yr[h + 1];
      r2 += yr[h + 2];
      r3 += yr[h + 3];
    }
    const int t_out = c * CH_ + lane;
    if (t_out < NT_) out[t_out * NS_ + site] = ((r0 + r1) + (r2 + r3)) + qb;

    // stage next chunk's met (all reads above already issued; DS in-order)
    if (c + 1 < NCHUNK_) smet[wv][lane] = compute_met(xnext);
  }
}

extern "C" void kernel_launch(void* const* d_in, const int* in_sizes, int n_in,
                              void* d_out, int out_size, void* d_ws, size_t ws_size,
                              hipStream_t stream) {
  const float* x    = (const float*)d_in[0];
  const float* xc   = (const float*)d_in[1];
  const float* fc_w = (const float*)d_in[2];
  const float* fc_b = (const float*)d_in[3];
  float* out = (float*)d_out;

  // 1024 sites, one wave each; 4 waves/block -> 256 blocks, 1 wave/SIMD
  // across the full machine (sites == SIMDs: max spread, zero interference).
  hipLaunchKernelGGL(waternet_scan, dim3(NS_ / 4), dim3(256), 0, stream,
                     x, xc, fc_w, fc_b, out);
}